// Round 6
// baseline (216.778 us; speedup 1.0000x reference)
//
#include <hip/hip_runtime.h>
#include <cstdint>
#include <cstddef>

// Problem dims (fixed by setup_inputs): b=4096, d=n=1024, k=4
#define NB 4096
#define ND 1024

typedef unsigned short ushortT;
typedef short short8 __attribute__((ext_vector_type(8)));
typedef float f32x4 __attribute__((ext_vector_type(4)));

__device__ __forceinline__ ushortT f2bf(float f) {
    unsigned u = __float_as_uint(f);
    u += 0x7FFFu + ((u >> 16) & 1u);      // round-to-nearest-even
    return (ushortT)(u >> 16);
}
__device__ __forceinline__ float bf2f(ushortT b) {
    return __uint_as_float(((unsigned)b) << 16);
}
__device__ __forceinline__ float wave_sum(float v) {
    #pragma unroll
    for (int o = 1; o < 64; o <<= 1) v += __shfl_xor(v, o, 64);
    return v;
}

// --- prep: wave-per-row, no block barriers (proven round 5) ------------------
__global__ void prep_all(const float* __restrict__ x,
                         const float* __restrict__ mu1, const float* __restrict__ v1,
                         const float* __restrict__ mu2, const float* __restrict__ v2,
                         ushortT* __restrict__ xh, ushortT* __restrict__ W1,
                         ushortT* __restrict__ W2,
                         float* __restrict__ xx1,
                         float* __restrict__ mm1, float* __restrict__ vmu1,
                         float* __restrict__ mm2, float* __restrict__ vmu2,
                         float* __restrict__ statz) {
    const int gid = blockIdx.x * 256 + threadIdx.x;
    if (gid < 4096) statz[gid] = 0.f;
    const int task = gid >> 6;
    const int l = gid & 63;
    if (task < 4096) {
        const float* row = x + (size_t)task * ND;
        ushortT* orow = xh + (size_t)task * ND;
        float s = 0.f;
        #pragma unroll
        for (int j = 0; j < 4; ++j) {
            int c = (j * 64 + l) * 4;
            float4 xv = *reinterpret_cast<const float4*>(row + c);
            ushortT b0 = f2bf(xv.x), b1 = f2bf(xv.y), b2 = f2bf(xv.z), b3 = f2bf(xv.w);
            *reinterpret_cast<ushort4*>(orow + c) = make_ushort4(b0, b1, b2, b3);
            float r0 = bf2f(b0), r1 = bf2f(b1), r2 = bf2f(b2), r3 = bf2f(b3);
            s += r0 * r0 + r1 * r1 + r2 * r2 + r3 * r3;
        }
        s = wave_sum(s);
        if (l == 0) xx1[task] = s;
    } else {
        int tt = task - 4096;
        const int layer = tt >= 5120;
        if (layer) tt -= 5120;
        const float* mu = layer ? mu2 : mu1;
        const float* v  = layer ? v2  : v1;
        ushortT* W      = layer ? W2  : W1;
        float* mm       = layer ? mm2 : mm1;
        float* vmu      = layer ? vmu2 : vmu1;
        const int t = tt >> 10, n = tt & 1023;
        const float* src = (t == 0) ? (mu + (size_t)n * ND)
                                    : (v + ((size_t)n * 4 + (t - 1)) * ND);
        const float* murow = mu + (size_t)n * ND;
        ushortT* dst = W + ((size_t)t * 1024 + n) * ND;
        float s = 0.f;
        #pragma unroll
        for (int j = 0; j < 4; ++j) {
            int c = (j * 64 + l) * 4;
            float4 sv = *reinterpret_cast<const float4*>(src + c);
            float4 mv = *reinterpret_cast<const float4*>(murow + c);
            ushortT b0 = f2bf(sv.x), b1 = f2bf(sv.y), b2 = f2bf(sv.z), b3 = f2bf(sv.w);
            *reinterpret_cast<ushort4*>(dst + c) = make_ushort4(b0, b1, b2, b3);
            s += bf2f(b0) * bf2f(f2bf(mv.x)) + bf2f(b1) * bf2f(f2bf(mv.y))
               + bf2f(b2) * bf2f(f2bf(mv.z)) + bf2f(b3) * bf2f(f2bf(mv.w));
        }
        s = wave_sum(s);
        if (l == 0) {
            if (t == 0) mm[n] = s;
            else        vmu[n * 4 + (t - 1)] = s;
        }
    }
}

// --- layer-1 GEMM (round-2/5 structure, proven) ------------------------------
__launch_bounds__(256, 2)
__global__ void gemm_hmu1(const ushortT* __restrict__ Xh, const ushortT* __restrict__ Wh,
                          const float* __restrict__ xx, const float* __restrict__ mm,
                          const float* __restrict__ vmu, const float* __restrict__ lam,
                          ushortT* __restrict__ Ub,
                          float* __restrict__ sum, float* __restrict__ sumsq) {
    __shared__ ushortT As[128 * 64];        // 16 KB
    __shared__ ushortT Bs[5 * 64 * 64];     // 40 KB
    const int tid = threadIdx.x;
    const int lane = tid & 63, wave = tid >> 6;
    const int n0 = (blockIdx.x & 15) * 64;
    const int m0 = (blockIdx.x >> 4) * 128;

    f32x4 acc[8][5];
    #pragma unroll
    for (int mf = 0; mf < 8; ++mf)
        #pragma unroll
        for (int t = 0; t < 5; ++t)
            acc[mf][t] = (f32x4){0.f, 0.f, 0.f, 0.f};

    const int lrow8 = lane >> 3;
    const int lp    = lane & 7;

    for (int kt = 0; kt < 16; ++kt) {
        const int k0 = kt * 64;
        #pragma unroll
        for (int q = 0; q < 4; ++q) {          // A: 16 chunks of 1KB
            int chunk = q * 4 + wave;
            int row = chunk * 8 + lrow8;
            int s = lp ^ (row & 7);
            const ushortT* src = Xh + (size_t)(m0 + row) * ND + k0 + s * 8;
            __builtin_amdgcn_global_load_lds(
                (const __attribute__((address_space(1))) void*)src,
                (__attribute__((address_space(3))) void*)(As + chunk * 512), 16, 0, 0);
        }
        #pragma unroll
        for (int q = 0; q < 10; ++q) {         // B: 40 chunks (5 panels x 64 rows)
            int chunk = q * 4 + wave;
            int row = chunk * 8 + lrow8;
            int t = row >> 6, rr = row & 63;
            int s = lp ^ (row & 7);
            const ushortT* src = Wh + ((size_t)t * 1024 + n0 + rr) * ND + k0 + s * 8;
            __builtin_amdgcn_global_load_lds(
                (const __attribute__((address_space(1))) void*)src,
                (__attribute__((address_space(3))) void*)(Bs + chunk * 512), 16, 0, 0);
        }
        __syncthreads();
        #pragma unroll
        for (int i = 0; i < 2; ++i) {
            short8 av[8];
            #pragma unroll
            for (int mf = 0; mf < 8; ++mf) {
                int row = mf * 16 + (lane & 15);
                int sl = (4 * i + (lane >> 4)) ^ (row & 7);
                av[mf] = *reinterpret_cast<const short8*>(&As[row * 64 + sl * 8]);
            }
            #pragma unroll
            for (int t = 0; t < 5; ++t) {
                int rr = wave * 16 + (lane & 15);
                int sl = (4 * i + (lane >> 4)) ^ (rr & 7);
                short8 bv = *reinterpret_cast<const short8*>(&Bs[(t * 64 + rr) * 64 + sl * 8]);
                #pragma unroll
                for (int mf = 0; mf < 8; ++mf)
                    acc[mf][t] = __builtin_amdgcn_mfma_f32_16x16x32_bf16(av[mf], bv, acc[mf][t], 0, 0, 0);
            }
        }
        __syncthreads();
    }

    const int col = n0 + wave * 16 + (lane & 15);
    const float lamc = lam[col], mmc = mm[col];
    const float4 vm = *reinterpret_cast<const float4*>(vmu + col * 4);
    float csum = 0.f, csq = 0.f;
    #pragma unroll
    for (int mf = 0; mf < 8; ++mf) {
        #pragma unroll
        for (int i = 0; i < 4; ++i) {
            int brow = m0 + mf * 16 + (lane >> 4) * 4 + i;
            float s0 = acc[mf][0][i];
            float p0 = acc[mf][1][i] - vm.x;
            float p1 = acc[mf][2][i] - vm.y;
            float p2 = acc[mf][3][i] - vm.z;
            float p3 = acc[mf][4][i] - vm.w;
            float q = lamc * (xx[brow] - 2.f * s0 + mmc)
                    + p0 * p0 + p1 * p1 + p2 * p2 + p3 * p3;
            float xq = q * (1.0f / 1024.0f);
            float u = -xq * (1.0f - xq * (0.5f - xq * 0.16666667f));  // expm1(-x)
            ushortT ub = f2bf(u);
            Ub[(size_t)brow * ND + col] = ub;
            float ur = bf2f(ub);
            csum += ur; csq += ur * ur;
        }
    }
    csum += __shfl_xor(csum, 16); csum += __shfl_xor(csum, 32);
    csq  += __shfl_xor(csq, 16);  csq  += __shfl_xor(csq, 32);
    if (lane < 16) {
        atomicAdd(&sum[col], csum);
        atomicAdd(&sumsq[col], csq);
    }
}

// --- layer-2 GEMM with BN1 fused into A-staging ------------------------------
// A-staging: reg-stage U1 (bf16) -> h = u*a + c -> bf16 -> swizzled ds_write
// (write-side XOR, same involution; compute reads unchanged). Per-row ||h||^2
// accumulates during staging (thread t owns row t>>1, k-half t&1) -> xr[] LDS
// replaces xx2. B-staging / compute / epilogue identical to gemm_hmu1.
__launch_bounds__(256, 2)
__global__ void gemm2_fused(const ushortT* __restrict__ U1, const ushortT* __restrict__ Wh,
                            const float* __restrict__ s1, const float* __restrict__ q1,
                            const float* __restrict__ g1, const float* __restrict__ be1,
                            const float* __restrict__ mm, const float* __restrict__ vmu,
                            const float* __restrict__ lam,
                            float* __restrict__ U2,
                            float* __restrict__ sum, float* __restrict__ sumsq) {
    __shared__ ushortT As[128 * 64];        // 16 KB
    __shared__ ushortT Bs[5 * 64 * 64];     // 40 KB
    __shared__ float aT[1024];              // 4 KB  BN1 scale
    __shared__ float cT[1024];              // 4 KB  BN1 shift
    __shared__ float xr[128];               // row norms ||h||^2 for this m-strip
    const int tid = threadIdx.x;
    const int lane = tid & 63, wave = tid >> 6;
    const int n0 = (blockIdx.x & 15) * 64;
    const int m0 = (blockIdx.x >> 4) * 128;

    // build BN1 affine tables (4 cols/thread); stats complete (stream-ordered)
    {
        const int c4 = tid * 4;
        float4 sv = *reinterpret_cast<const float4*>(s1 + c4);
        float4 qv = *reinterpret_cast<const float4*>(q1 + c4);
        float4 gv = *reinterpret_cast<const float4*>(g1 + c4);
        float4 bv = *reinterpret_cast<const float4*>(be1 + c4);
        float4 av, cv;
        {
            float m = sv.x * (1.f/4096.f), var = qv.x * (1.f/4096.f) - m * m;
            av.x = rsqrtf(var + 1e-5f) * gv.x; cv.x = bv.x - m * av.x;
        }
        {
            float m = sv.y * (1.f/4096.f), var = qv.y * (1.f/4096.f) - m * m;
            av.y = rsqrtf(var + 1e-5f) * gv.y; cv.y = bv.y - m * av.y;
        }
        {
            float m = sv.z * (1.f/4096.f), var = qv.z * (1.f/4096.f) - m * m;
            av.z = rsqrtf(var + 1e-5f) * gv.z; cv.z = bv.z - m * av.z;
        }
        {
            float m = sv.w * (1.f/4096.f), var = qv.w * (1.f/4096.f) - m * m;
            av.w = rsqrtf(var + 1e-5f) * gv.w; cv.w = bv.w - m * av.w;
        }
        *reinterpret_cast<float4*>(aT + c4) = av;
        *reinterpret_cast<float4*>(cT + c4) = cv;
    }
    __syncthreads();

    f32x4 acc[8][5];
    #pragma unroll
    for (int mf = 0; mf < 8; ++mf)
        #pragma unroll
        for (int t = 0; t < 5; ++t)
            acc[mf][t] = (f32x4){0.f, 0.f, 0.f, 0.f};

    const int lrow8 = lane >> 3;
    const int lp    = lane & 7;
    const int ar = tid >> 1;                // A-staging: row 0..127
    const int ah = (tid & 1) * 4;           // logical slot base (0 or 4)
    float rowacc = 0.f;

    for (int kt = 0; kt < 16; ++kt) {
        const int k0 = kt * 64;
        // B: global_load_lds (issue first, latency overlaps A's VALU)
        #pragma unroll
        for (int q = 0; q < 10; ++q) {
            int chunk = q * 4 + wave;
            int row = chunk * 8 + lrow8;
            int t = row >> 6, rr = row & 63;
            int s = lp ^ (row & 7);
            const ushortT* src = Wh + ((size_t)t * 1024 + n0 + rr) * ND + k0 + s * 8;
            __builtin_amdgcn_global_load_lds(
                (const __attribute__((address_space(1))) void*)src,
                (__attribute__((address_space(3))) void*)(Bs + chunk * 512), 16, 0, 0);
        }
        // A: reg-stage + BN1 affine + row-norm accumulation
        #pragma unroll
        for (int j = 0; j < 4; ++j) {
            const int ls = ah + j;
            const int kb = k0 + ls * 8;
            short8 uv = *reinterpret_cast<const short8*>(U1 + (size_t)(m0 + ar) * ND + kb);
            float aa[8], cc[8];
            *reinterpret_cast<float4*>(aa)     = *reinterpret_cast<const float4*>(aT + kb);
            *reinterpret_cast<float4*>(aa + 4) = *reinterpret_cast<const float4*>(aT + kb + 4);
            *reinterpret_cast<float4*>(cc)     = *reinterpret_cast<const float4*>(cT + kb);
            *reinterpret_cast<float4*>(cc + 4) = *reinterpret_cast<const float4*>(cT + kb + 4);
            short8 hv;
            #pragma unroll
            for (int e = 0; e < 8; ++e) {
                float h = bf2f((ushortT)uv[e]) * aa[e] + cc[e];
                ushortT hb = f2bf(h);
                float hr = bf2f(hb);
                rowacc += hr * hr;
                hv[e] = (short)hb;
            }
            *reinterpret_cast<short8*>(&As[ar * 64 + (ls ^ (ar & 7)) * 8]) = hv;
        }
        __syncthreads();
        #pragma unroll
        for (int i = 0; i < 2; ++i) {
            short8 av[8];
            #pragma unroll
            for (int mf = 0; mf < 8; ++mf) {
                int row = mf * 16 + (lane & 15);
                int sl = (4 * i + (lane >> 4)) ^ (row & 7);
                av[mf] = *reinterpret_cast<const short8*>(&As[row * 64 + sl * 8]);
            }
            #pragma unroll
            for (int t = 0; t < 5; ++t) {
                int rr = wave * 16 + (lane & 15);
                int sl = (4 * i + (lane >> 4)) ^ (rr & 7);
                short8 bv = *reinterpret_cast<const short8*>(&Bs[(t * 64 + rr) * 64 + sl * 8]);
                #pragma unroll
                for (int mf = 0; mf < 8; ++mf)
                    acc[mf][t] = __builtin_amdgcn_mfma_f32_16x16x32_bf16(av[mf], bv, acc[mf][t], 0, 0, 0);
            }
        }
        __syncthreads();
    }

    // publish per-row ||h||^2
    {
        float other = __shfl_xor(rowacc, 1);
        if ((tid & 1) == 0) xr[ar] = rowacc + other;
    }
    __syncthreads();

    const int col = n0 + wave * 16 + (lane & 15);
    const float lamc = lam[col], mmc = mm[col];
    const float4 vm = *reinterpret_cast<const float4*>(vmu + col * 4);
    float csum = 0.f, csq = 0.f;
    #pragma unroll
    for (int mf = 0; mf < 8; ++mf) {
        #pragma unroll
        for (int i = 0; i < 4; ++i) {
            int lrow = mf * 16 + (lane >> 4) * 4 + i;
            float s0 = acc[mf][0][i];
            float p0 = acc[mf][1][i] - vm.x;
            float p1 = acc[mf][2][i] - vm.y;
            float p2 = acc[mf][3][i] - vm.z;
            float p3 = acc[mf][4][i] - vm.w;
            float q = lamc * (xr[lrow] - 2.f * s0 + mmc)
                    + p0 * p0 + p1 * p1 + p2 * p2 + p3 * p3;
            float xq = q * (1.0f / 1024.0f);
            float u = -xq * (1.0f - xq * (0.5f - xq * 0.16666667f));  // expm1(-x)
            U2[(size_t)(m0 + lrow) * ND + col] = u;
            csum += u; csq += u * u;
        }
    }
    csum += __shfl_xor(csum, 16); csum += __shfl_xor(csum, 32);
    csq  += __shfl_xor(csq, 16);  csq  += __shfl_xor(csq, 32);
    if (lane < 16) {
        atomicAdd(&sum[col], csum);
        atomicAdd(&sumsq[col], csq);
    }
}

// --- BN2 apply + identity shortcut (wave-per-row) ----------------------------
__global__ void bn_apply_out(const float* __restrict__ U, const float* __restrict__ sum,
                             const float* __restrict__ sumsq, const float* __restrict__ g,
                             const float* __restrict__ beta, const float* __restrict__ x,
                             float* __restrict__ out) {
    const int gid = blockIdx.x * 256 + threadIdx.x;
    const int row = gid >> 6, l = gid & 63;
    const float* urow = U + (size_t)row * ND;
    const float* xrow = x + (size_t)row * ND;
    float* orow = out + (size_t)row * ND;
    #pragma unroll
    for (int j = 0; j < 4; ++j) {
        int c = (j * 64 + l) * 4;
        float4 uv = *reinterpret_cast<const float4*>(urow + c);
        float4 xv = *reinterpret_cast<const float4*>(xrow + c);
        float4 sv = *reinterpret_cast<const float4*>(sum + c);
        float4 qv = *reinterpret_cast<const float4*>(sumsq + c);
        float4 gv = *reinterpret_cast<const float4*>(g + c);
        float4 bv = *reinterpret_cast<const float4*>(beta + c);
        float4 ov;
        {
            float m = sv.x * (1.0f/4096.0f), var = qv.x * (1.0f/4096.0f) - m*m;
            float a = rsqrtf(var + 1e-5f) * gv.x; ov.x = (uv.x - m) * a + bv.x + xv.x;
        }
        {
            float m = sv.y * (1.0f/4096.0f), var = qv.y * (1.0f/4096.0f) - m*m;
            float a = rsqrtf(var + 1e-5f) * gv.y; ov.y = (uv.y - m) * a + bv.y + xv.y;
        }
        {
            float m = sv.z * (1.0f/4096.0f), var = qv.z * (1.0f/4096.0f) - m*m;
            float a = rsqrtf(var + 1e-5f) * gv.z; ov.z = (uv.z - m) * a + bv.z + xv.z;
        }
        {
            float m = sv.w * (1.0f/4096.0f), var = qv.w * (1.0f/4096.0f) - m*m;
            float a = rsqrtf(var + 1e-5f) * gv.w; ov.w = (uv.w - m) * a + bv.w + xv.w;
        }
        *reinterpret_cast<float4*>(orow + c) = ov;
    }
}

extern "C" void kernel_launch(void* const* d_in, const int* in_sizes, int n_in,
                              void* d_out, int out_size, void* d_ws, size_t ws_size,
                              hipStream_t stream) {
    const float* x    = (const float*)d_in[0];
    const float* mu1  = (const float*)d_in[1];
    const float* lam1 = (const float*)d_in[2];
    const float* v1   = (const float*)d_in[3];
    const float* g1   = (const float*)d_in[4];
    const float* b1   = (const float*)d_in[5];
    const float* mu2  = (const float*)d_in[6];
    const float* lam2 = (const float*)d_in[7];
    const float* v2   = (const float*)d_in[8];
    const float* g2   = (const float*)d_in[9];
    const float* b2   = (const float*)d_in[10];
    float* out = (float*)d_out;
    char* ws = (char*)d_ws;
    const size_t MB = 1024 * 1024;

    // workspace layout (lifetime-overlapped):
    // [0,8)MB xh ; [8,18)MB W1 ; U2(f32,16MB) aliases [0,16) after gemm1 retires xh/W1
    // [26,36)MB W2 ; [36,44)MB U1(bf16) ; [44MB,..) stats
    ushortT* xh  = (ushortT*)(ws + 0);
    ushortT* W1  = (ushortT*)(ws + 8 * MB);
    float*   U2  = (float*)  (ws + 0);
    ushortT* W2  = (ushortT*)(ws + 26 * MB);
    ushortT* U1  = (ushortT*)(ws + 36 * MB);
    char* st = ws + 44 * MB;
    float* xx1    = (float*)(st + 0);
    float* mm1    = (float*)(st + 32768);
    float* mm2    = (float*)(st + 36864);
    float* vmu1   = (float*)(st + 40960);
    float* vmu2   = (float*)(st + 57344);
    float* sum1   = (float*)(st + 73728);   // sum1,sumsq1,sum2,sumsq2 contiguous 16KB
    float* sumsq1 = (float*)(st + 77824);
    float* sum2   = (float*)(st + 81920);
    float* sumsq2 = (float*)(st + 86016);

    const size_t needed = 44 * MB + 90112;
    if (ws_size < needed) return;

    prep_all<<<3584, 256, 0, stream>>>(x, mu1, v1, mu2, v2, xh, W1, W2,
                                       xx1, mm1, vmu1, mm2, vmu2, sum1);

    gemm_hmu1<<<512, 256, 0, stream>>>(xh, W1, xx1, mm1, vmu1, lam1,
                                       U1, sum1, sumsq1);

    gemm2_fused<<<512, 256, 0, stream>>>(U1, W2, sum1, sumsq1, g1, b1,
                                         mm2, vmu2, lam2, U2, sum2, sumsq2);

    bn_apply_out<<<1024, 256, 0, stream>>>(U2, sum2, sumsq2, g2, b2, x, out);
}

// Round 7
// 209.858 us; speedup vs baseline: 1.0330x; 1.0330x over previous
//
#include <hip/hip_runtime.h>
#include <cstdint>
#include <cstddef>

// Problem dims (fixed by setup_inputs): b=4096, d=n=1024, k=4
#define NB 4096
#define ND 1024

typedef unsigned short ushortT;
typedef short short8 __attribute__((ext_vector_type(8)));
typedef float f32x4 __attribute__((ext_vector_type(4)));

__device__ __forceinline__ ushortT f2bf(float f) {
    unsigned u = __float_as_uint(f);
    u += 0x7FFFu + ((u >> 16) & 1u);      // round-to-nearest-even
    return (ushortT)(u >> 16);
}
__device__ __forceinline__ float bf2f(ushortT b) {
    return __uint_as_float(((unsigned)b) << 16);
}
__device__ __forceinline__ float wave_sum(float v) {
    #pragma unroll
    for (int o = 1; o < 64; o <<= 1) v += __shfl_xor(v, o, 64);
    return v;
}

// --- prep: wave-per-row, no block barriers (proven round 5) ------------------
__global__ void prep_all(const float* __restrict__ x,
                         const float* __restrict__ mu1, const float* __restrict__ v1,
                         const float* __restrict__ mu2, const float* __restrict__ v2,
                         ushortT* __restrict__ xh, ushortT* __restrict__ W1,
                         ushortT* __restrict__ W2,
                         float* __restrict__ xx1,
                         float* __restrict__ mm1, float* __restrict__ vmu1,
                         float* __restrict__ mm2, float* __restrict__ vmu2,
                         float* __restrict__ statz) {
    const int gid = blockIdx.x * 256 + threadIdx.x;
    if (gid < 4096) statz[gid] = 0.f;
    const int task = gid >> 6;
    const int l = gid & 63;
    if (task < 4096) {
        const float* row = x + (size_t)task * ND;
        ushortT* orow = xh + (size_t)task * ND;
        float s = 0.f;
        #pragma unroll
        for (int j = 0; j < 4; ++j) {
            int c = (j * 64 + l) * 4;
            float4 xv = *reinterpret_cast<const float4*>(row + c);
            ushortT b0 = f2bf(xv.x), b1 = f2bf(xv.y), b2 = f2bf(xv.z), b3 = f2bf(xv.w);
            *reinterpret_cast<ushort4*>(orow + c) = make_ushort4(b0, b1, b2, b3);
            float r0 = bf2f(b0), r1 = bf2f(b1), r2 = bf2f(b2), r3 = bf2f(b3);
            s += r0 * r0 + r1 * r1 + r2 * r2 + r3 * r3;
        }
        s = wave_sum(s);
        if (l == 0) xx1[task] = s;
    } else {
        int tt = task - 4096;
        const int layer = tt >= 5120;
        if (layer) tt -= 5120;
        const float* mu = layer ? mu2 : mu1;
        const float* v  = layer ? v2  : v1;
        ushortT* W      = layer ? W2  : W1;
        float* mm       = layer ? mm2 : mm1;
        float* vmu      = layer ? vmu2 : vmu1;
        const int t = tt >> 10, n = tt & 1023;
        const float* src = (t == 0) ? (mu + (size_t)n * ND)
                                    : (v + ((size_t)n * 4 + (t - 1)) * ND);
        const float* murow = mu + (size_t)n * ND;
        ushortT* dst = W + ((size_t)t * 1024 + n) * ND;
        float s = 0.f;
        #pragma unroll
        for (int j = 0; j < 4; ++j) {
            int c = (j * 64 + l) * 4;
            float4 sv = *reinterpret_cast<const float4*>(src + c);
            float4 mv = *reinterpret_cast<const float4*>(murow + c);
            ushortT b0 = f2bf(sv.x), b1 = f2bf(sv.y), b2 = f2bf(sv.z), b3 = f2bf(sv.w);
            *reinterpret_cast<ushort4*>(dst + c) = make_ushort4(b0, b1, b2, b3);
            s += bf2f(b0) * bf2f(f2bf(mv.x)) + bf2f(b1) * bf2f(f2bf(mv.y))
               + bf2f(b2) * bf2f(f2bf(mv.z)) + bf2f(b3) * bf2f(f2bf(mv.w));
        }
        s = wave_sum(s);
        if (l == 0) {
            if (t == 0) mm[n] = s;
            else        vmu[n * 4 + (t - 1)] = s;
        }
    }
}

// --- fused 5-panel HMU GEMM, BK=32 double-buffered counted-vmcnt -------------
// Tile: 128(M) x 64(n) x 5 panels, 4 waves, 2 x 28KB LDS = 56KB, 2 blk/CU.
// Per K-tile (K=32): issue 7 global_load_lds for tile kt+1 -> vmcnt(7)
// (tile kt's 7 loads complete; never drain to 0 mid-loop) -> raw s_barrier ->
// 13 ds_read_b128 + 40 MFMA -> raw s_barrier. 4-slot rows (64B), XOR swizzle
// s = p ^ (row&3): linear LDS dest, inverse-swizzled global src, swizzled read
// (2-way bank alias on read = free).
__launch_bounds__(256, 2)
__global__ void gemm_hmu(const ushortT* __restrict__ Xh, const ushortT* __restrict__ Wh,
                         const float* __restrict__ xx, const float* __restrict__ mm,
                         const float* __restrict__ vmu, const float* __restrict__ lam,
                         ushortT* __restrict__ Ub,
                         float* __restrict__ sum, float* __restrict__ sumsq) {
    __shared__ ushortT lds[2 * 14336];     // 2 x (A: 4096 + B: 10240 ushorts)
    const int tid = threadIdx.x;
    const int lane = tid & 63, wave = tid >> 6;
    const int n0 = (blockIdx.x & 15) * 64;
    const int m0 = (blockIdx.x >> 4) * 128;

    f32x4 acc[8][5];
    #pragma unroll
    for (int mf = 0; mf < 8; ++mf)
        #pragma unroll
        for (int t = 0; t < 5; ++t)
            acc[mf][t] = (f32x4){0.f, 0.f, 0.f, 0.f};

    // staging geometry: row stride 64B = 4 lanes x 16B; wave covers 16 rows/round
    const int srow = wave * 16 + (lane >> 2);   // row within a 64-row round
    const int sp   = lane & 3;                  // physical 16B slot

    auto stage = [&](int buf, int kt) {
        const int k0 = kt * 32;
        ushortT* Ad = lds + buf * 14336;
        ushortT* Bd = Ad + 4096;
        #pragma unroll
        for (int q = 0; q < 2; ++q) {           // A: 128 rows x 64B
            int row = q * 64 + srow;
            int s = sp ^ (row & 3);
            const ushortT* src = Xh + (size_t)(m0 + row) * ND + k0 + s * 8;
            __builtin_amdgcn_global_load_lds(
                (const __attribute__((address_space(1))) void*)src,
                (__attribute__((address_space(3))) void*)(Ad + q * 2048 + wave * 512),
                16, 0, 0);
        }
        #pragma unroll
        for (int q = 0; q < 5; ++q) {           // B: 320 stack rows x 64B
            int row = q * 64 + srow;
            int t = row >> 6, rr = row & 63;
            int s = sp ^ (row & 3);
            const ushortT* src = Wh + ((size_t)t * 1024 + n0 + rr) * ND + k0 + s * 8;
            __builtin_amdgcn_global_load_lds(
                (const __attribute__((address_space(1))) void*)src,
                (__attribute__((address_space(3))) void*)(Bd + q * 2048 + wave * 512),
                16, 0, 0);
        }
    };

    auto compute = [&](int buf) {
        const ushortT* Ab = lds + buf * 14336;
        const ushortT* Bb = Ab + 4096;
        short8 av[8];
        #pragma unroll
        for (int mf = 0; mf < 8; ++mf) {
            int row = mf * 16 + (lane & 15);
            int sl = (lane >> 4) ^ (row & 3);
            av[mf] = *reinterpret_cast<const short8*>(&Ab[row * 32 + sl * 8]);
        }
        #pragma unroll
        for (int t = 0; t < 5; ++t) {
            int rr = wave * 16 + (lane & 15);
            int sl = (lane >> 4) ^ (rr & 3);
            short8 bv = *reinterpret_cast<const short8*>(&Bb[(t * 64 + rr) * 32 + sl * 8]);
            #pragma unroll
            for (int mf = 0; mf < 8; ++mf)
                acc[mf][t] = __builtin_amdgcn_mfma_f32_16x16x32_bf16(av[mf], bv, acc[mf][t], 0, 0, 0);
        }
    };

    stage(0, 0);
    for (int kt = 0; kt < 31; ++kt) {
        stage((kt + 1) & 1, kt + 1);                       // 7 loads in flight on top
        asm volatile("s_waitcnt vmcnt(7)" ::: "memory");   // tile kt's 7 loads done
        __builtin_amdgcn_s_barrier();
        __builtin_amdgcn_sched_barrier(0);                 // ds_reads stay below barrier
        compute(kt & 1);
        __builtin_amdgcn_sched_barrier(0);                 // ds_reads stay above barrier
        __builtin_amdgcn_s_barrier();                      // buf kt free for overwrite
    }
    asm volatile("s_waitcnt vmcnt(0)" ::: "memory");
    __builtin_amdgcn_s_barrier();
    __builtin_amdgcn_sched_barrier(0);
    compute(1);

    // epilogue: u = expm1(-q/1024) cubic; bf16 store; fused column stats
    const int col = n0 + wave * 16 + (lane & 15);
    const float lamc = lam[col], mmc = mm[col];
    const float4 vm = *reinterpret_cast<const float4*>(vmu + col * 4);
    float csum = 0.f, csq = 0.f;
    #pragma unroll
    for (int mf = 0; mf < 8; ++mf) {
        #pragma unroll
        for (int i = 0; i < 4; ++i) {
            int brow = m0 + mf * 16 + (lane >> 4) * 4 + i;
            float s0 = acc[mf][0][i];
            float p0 = acc[mf][1][i] - vm.x;
            float p1 = acc[mf][2][i] - vm.y;
            float p2 = acc[mf][3][i] - vm.z;
            float p3 = acc[mf][4][i] - vm.w;
            float q = lamc * (xx[brow] - 2.f * s0 + mmc)
                    + p0 * p0 + p1 * p1 + p2 * p2 + p3 * p3;
            float xq = q * (1.0f / 1024.0f);
            float u = -xq * (1.0f - xq * (0.5f - xq * 0.16666667f));  // expm1(-x)
            ushortT ub = f2bf(u);
            Ub[(size_t)brow * ND + col] = ub;
            float ur = bf2f(ub);
            csum += ur; csq += ur * ur;
        }
    }
    csum += __shfl_xor(csum, 16); csum += __shfl_xor(csum, 32);
    csq  += __shfl_xor(csq, 16);  csq  += __shfl_xor(csq, 32);
    if (lane < 16) {
        atomicAdd(&sum[col], csum);
        atomicAdd(&sumsq[col], csq);
    }
}

// --- BN1 apply -> h (bf16) + post-round row norms (wave-per-row) -------------
__global__ void bn_apply_h(const ushortT* __restrict__ U, const float* __restrict__ sum,
                           const float* __restrict__ sumsq, const float* __restrict__ g,
                           const float* __restrict__ beta, ushortT* __restrict__ hh,
                           float* __restrict__ xx2) {
    const int gid = blockIdx.x * 256 + threadIdx.x;
    const int row = gid >> 6, l = gid & 63;
    const ushortT* urow = U + (size_t)row * ND;
    ushortT* hrow = hh + (size_t)row * ND;
    float s = 0.f;
    #pragma unroll
    for (int j = 0; j < 4; ++j) {
        int c = (j * 64 + l) * 4;
        ushort4 uv = *reinterpret_cast<const ushort4*>(urow + c);
        float4 sv = *reinterpret_cast<const float4*>(sum + c);
        float4 qv = *reinterpret_cast<const float4*>(sumsq + c);
        float4 gv = *reinterpret_cast<const float4*>(g + c);
        float4 bv = *reinterpret_cast<const float4*>(beta + c);
        float ua[4] = {bf2f(uv.x), bf2f(uv.y), bf2f(uv.z), bf2f(uv.w)};
        float sa[4] = {sv.x, sv.y, sv.z, sv.w};
        float qa[4] = {qv.x, qv.y, qv.z, qv.w};
        float ga[4] = {gv.x, gv.y, gv.z, gv.w};
        float ba[4] = {bv.x, bv.y, bv.z, bv.w};
        ushortT hb[4];
        #pragma unroll
        for (int e = 0; e < 4; ++e) {
            float m = sa[e] * (1.0f / 4096.0f);
            float var = qa[e] * (1.0f / 4096.0f) - m * m;
            float a = rsqrtf(var + 1e-5f) * ga[e];
            float h = (ua[e] - m) * a + ba[e];
            hb[e] = f2bf(h);
            float hr = bf2f(hb[e]);
            s += hr * hr;
        }
        *reinterpret_cast<ushort4*>(hrow + c) = make_ushort4(hb[0], hb[1], hb[2], hb[3]);
    }
    s = wave_sum(s);
    if (l == 0) xx2[row] = s;
}

// --- BN2 apply + identity shortcut (wave-per-row; U2 is bf16) ----------------
__global__ void bn_apply_out(const ushortT* __restrict__ U, const float* __restrict__ sum,
                             const float* __restrict__ sumsq, const float* __restrict__ g,
                             const float* __restrict__ beta, const float* __restrict__ x,
                             float* __restrict__ out) {
    const int gid = blockIdx.x * 256 + threadIdx.x;
    const int row = gid >> 6, l = gid & 63;
    const ushortT* urow = U + (size_t)row * ND;
    const float* xrow = x + (size_t)row * ND;
    float* orow = out + (size_t)row * ND;
    #pragma unroll
    for (int j = 0; j < 4; ++j) {
        int c = (j * 64 + l) * 4;
        ushort4 uv = *reinterpret_cast<const ushort4*>(urow + c);
        float4 xv = *reinterpret_cast<const float4*>(xrow + c);
        float4 sv = *reinterpret_cast<const float4*>(sum + c);
        float4 qv = *reinterpret_cast<const float4*>(sumsq + c);
        float4 gv = *reinterpret_cast<const float4*>(g + c);
        float4 bv = *reinterpret_cast<const float4*>(beta + c);
        float ua[4] = {bf2f(uv.x), bf2f(uv.y), bf2f(uv.z), bf2f(uv.w)};
        float4 ov;
        {
            float m = sv.x * (1.0f/4096.0f), var = qv.x * (1.0f/4096.0f) - m*m;
            float a = rsqrtf(var + 1e-5f) * gv.x; ov.x = (ua[0] - m) * a + bv.x + xv.x;
        }
        {
            float m = sv.y * (1.0f/4096.0f), var = qv.y * (1.0f/4096.0f) - m*m;
            float a = rsqrtf(var + 1e-5f) * gv.y; ov.y = (ua[1] - m) * a + bv.y + xv.y;
        }
        {
            float m = sv.z * (1.0f/4096.0f), var = qv.z * (1.0f/4096.0f) - m*m;
            float a = rsqrtf(var + 1e-5f) * gv.z; ov.z = (ua[2] - m) * a + bv.z + xv.z;
        }
        {
            float m = sv.w * (1.0f/4096.0f), var = qv.w * (1.0f/4096.0f) - m*m;
            float a = rsqrtf(var + 1e-5f) * gv.w; ov.w = (ua[3] - m) * a + bv.w + xv.w;
        }
        *reinterpret_cast<float4*>(orow + c) = ov;
    }
}

extern "C" void kernel_launch(void* const* d_in, const int* in_sizes, int n_in,
                              void* d_out, int out_size, void* d_ws, size_t ws_size,
                              hipStream_t stream) {
    const float* x    = (const float*)d_in[0];
    const float* mu1  = (const float*)d_in[1];
    const float* lam1 = (const float*)d_in[2];
    const float* v1   = (const float*)d_in[3];
    const float* g1   = (const float*)d_in[4];
    const float* b1   = (const float*)d_in[5];
    const float* mu2  = (const float*)d_in[6];
    const float* lam2 = (const float*)d_in[7];
    const float* v2   = (const float*)d_in[8];
    const float* g2   = (const float*)d_in[9];
    const float* b2   = (const float*)d_in[10];
    float* out = (float*)d_out;
    char* ws = (char*)d_ws;
    const size_t MB = 1024 * 1024;

    // workspace layout (lifetime-overlapped):
    // [0,8)MB xh / U2(bf16, aliases after gemm1 retires xh)
    // [8,18)MB W1 ; [18,26)MB hh ; [26,36)MB W2 ; [36,44)MB U1(bf16) ; [44MB,..) stats
    ushortT* xh  = (ushortT*)(ws + 0);
    ushortT* U2  = (ushortT*)(ws + 0);
    ushortT* W1  = (ushortT*)(ws + 8 * MB);
    ushortT* hh  = (ushortT*)(ws + 18 * MB);
    ushortT* W2  = (ushortT*)(ws + 26 * MB);
    ushortT* U1  = (ushortT*)(ws + 36 * MB);
    char* st = ws + 44 * MB;
    float* xx1    = (float*)(st + 0);
    float* xx2    = (float*)(st + 16384);
    float* mm1    = (float*)(st + 32768);
    float* mm2    = (float*)(st + 36864);
    float* vmu1   = (float*)(st + 40960);
    float* vmu2   = (float*)(st + 57344);
    float* sum1   = (float*)(st + 73728);   // sum1,sumsq1,sum2,sumsq2 contiguous 16KB
    float* sumsq1 = (float*)(st + 77824);
    float* sum2   = (float*)(st + 81920);
    float* sumsq2 = (float*)(st + 86016);

    const size_t needed = 44 * MB + 90112;
    if (ws_size < needed) return;

    prep_all<<<3584, 256, 0, stream>>>(x, mu1, v1, mu2, v2, xh, W1, W2,
                                       xx1, mm1, vmu1, mm2, vmu2, sum1);

    gemm_hmu<<<512, 256, 0, stream>>>(xh, W1, xx1, mm1, vmu1, lam1,
                                      U1, sum1, sumsq1);
    bn_apply_h<<<1024, 256, 0, stream>>>(U1, sum1, sumsq1, g1, b1, hh, xx2);

    gemm_hmu<<<512, 256, 0, stream>>>(hh, W2, xx2, mm2, vmu2, lam2,
                                      U2, sum2, sumsq2);
    bn_apply_out<<<1024, 256, 0, stream>>>(U2, sum2, sumsq2, g2, b2, x, out);
}